// Round 1
// baseline (1153.048 us; speedup 1.0000x reference)
//
#include <hip/hip_runtime.h>

#define HID 128
#define OUTF 101

// ---------------- CSR build ----------------

__global__ void deg_kernel(const int* __restrict__ dst, int E, int* __restrict__ deg) {
    int e = blockIdx.x * blockDim.x + threadIdx.x;
    if (e < E) atomicAdd(&deg[dst[e]], 1);
}

__global__ void dis_kernel(const int* __restrict__ deg, float* __restrict__ dis, int n) {
    int i = blockIdx.x * blockDim.x + threadIdx.x;
    if (i < n) dis[i] = rsqrtf((float)(deg[i] + 1));  // +1 self-loop; deg_total >= 1 always
}

// Single-block exclusive scan over n ints (n ~ 100k). 1024 threads, each owns a chunk.
__global__ __launch_bounds__(1024) void scan_kernel(const int* __restrict__ deg,
                                                    int* __restrict__ row_ptr, int n) {
    __shared__ int partial[1024];
    int tid = threadIdx.x;
    int chunk = (n + 1023) >> 10;
    int begin = tid * chunk;
    int end = begin + chunk;
    if (begin > n) begin = n;
    if (end > n) end = n;
    int sum = 0;
    for (int i = begin; i < end; ++i) sum += deg[i];
    partial[tid] = sum;
    __syncthreads();
    // Hillis-Steele inclusive scan of the 1024 partials
    for (int off = 1; off < 1024; off <<= 1) {
        int v = 0;
        if (tid >= off) v = partial[tid - off];
        __syncthreads();
        if (tid >= off) partial[tid] += v;
        __syncthreads();
    }
    int prefix = (tid == 0) ? 0 : partial[tid - 1];
    for (int i = begin; i < end; ++i) {
        row_ptr[i] = prefix;
        prefix += deg[i];
    }
    if (tid == 1023) row_ptr[n] = partial[1023];
}

__global__ void fill_csr_kernel(const int* __restrict__ src, const int* __restrict__ dst, int E,
                                const float* __restrict__ dis, int* __restrict__ cursor,
                                int* __restrict__ csr_src, float* __restrict__ csr_w) {
    int e = blockIdx.x * blockDim.x + threadIdx.x;
    if (e >= E) return;
    int s = src[e];
    int d = dst[e];
    int pos = atomicAdd(&cursor[d], 1);
    csr_src[pos] = s;
    csr_w[pos] = dis[s] * dis[d];
}

// ---------------- dense transforms ----------------

// h = x @ W1, x: [n,10], W1: [10,128]. One block per node, 128 threads.
__global__ void lin10_kernel(const float* __restrict__ x, const float* __restrict__ W,
                             float* __restrict__ h, int n) {
    int i = blockIdx.x;
    int j = threadIdx.x;
    __shared__ float xs[10];
    if (j < 10) xs[j] = x[(size_t)i * 10 + j];
    __syncthreads();
    float acc = 0.f;
#pragma unroll
    for (int k = 0; k < 10; ++k) acc += xs[k] * W[k * HID + j];
    h[(size_t)i * HID + j] = acc;
}

// out = in @ W, in: [n,128], W: [128,128]. NB nodes per block to amortize W reads.
template <int NB>
__global__ void lin128_kernel(const float* __restrict__ in, const float* __restrict__ W,
                              float* __restrict__ out, int n) {
    int j = threadIdx.x;
    int base = blockIdx.x * NB;
    __shared__ float xs[NB][HID];
#pragma unroll
    for (int m = 0; m < NB; ++m) {
        int i = base + m;
        xs[m][j] = (i < n) ? in[(size_t)i * HID + j] : 0.f;
    }
    __syncthreads();
    float acc[NB];
#pragma unroll
    for (int m = 0; m < NB; ++m) acc[m] = 0.f;
    for (int k = 0; k < HID; ++k) {
        float wv = W[k * HID + j];
#pragma unroll
        for (int m = 0; m < NB; ++m) acc[m] += xs[m][k] * wv;
    }
#pragma unroll
    for (int m = 0; m < NB; ++m) {
        int i = base + m;
        if (i < n) out[(size_t)i * HID + j] = acc[m];
    }
}

// ---------------- aggregation (the hot loop) ----------------
// out[i] = sum_{e in in-edges(i)} h[src_e] * w_e  +  h[i] * dis[i]^2  + b ; optional relu
__global__ void aggregate_kernel(const float* __restrict__ h, const int* __restrict__ row_ptr,
                                 const int* __restrict__ csr_src, const float* __restrict__ csr_w,
                                 const float* __restrict__ dis, const float* __restrict__ b,
                                 float* __restrict__ out, int n, int relu) {
    int i = blockIdx.x;
    int j = threadIdx.x;
    float di = dis[i];
    float acc = h[(size_t)i * HID + j] * (di * di);  // self-loop
    int beg = row_ptr[i];
    int end = row_ptr[i + 1];
    for (int e = beg; e < end; ++e) {
        int s = csr_src[e];
        float w = csr_w[e];
        acc += h[(size_t)s * HID + j] * w;
    }
    acc += b[j];
    if (relu) acc = fmaxf(acc, 0.f);
    out[(size_t)i * HID + j] = acc;
}

// ---------------- pooling + head ----------------

__global__ void pool_kernel(const float* __restrict__ h, const int* __restrict__ batch, int n,
                            float* __restrict__ sums) {
    int g = blockIdx.x;
    int j = threadIdx.x;
    int lo = 0, hi = n;
    while (lo < hi) { int mid = (lo + hi) >> 1; if (batch[mid] < g) lo = mid + 1; else hi = mid; }
    int start = lo;
    lo = start; hi = n;
    while (lo < hi) { int mid = (lo + hi) >> 1; if (batch[mid] < g + 1) lo = mid + 1; else hi = mid; }
    int end = lo;
    float acc = 0.f;
    for (int i = start + blockIdx.y; i < end; i += gridDim.y) acc += h[(size_t)i * HID + j];
    atomicAdd(&sums[g * HID + j], acc);
}

__global__ void final_kernel(const float* __restrict__ sums, const int* __restrict__ batch, int n,
                             const float* __restrict__ Wl, const float* __restrict__ bl,
                             float* __restrict__ out) {
    int g = blockIdx.x;
    int o = threadIdx.x;  // 128 threads; only o<101 produce output
    __shared__ float p[HID];
    int lo = 0, hi = n;
    while (lo < hi) { int mid = (lo + hi) >> 1; if (batch[mid] < g) lo = mid + 1; else hi = mid; }
    int start = lo;
    lo = start; hi = n;
    while (lo < hi) { int mid = (lo + hi) >> 1; if (batch[mid] < g + 1) lo = mid + 1; else hi = mid; }
    float cnt = fmaxf((float)(lo - start), 1.0f);
    p[o] = sums[g * HID + o] / cnt;
    __syncthreads();
    if (o < OUTF) {
        float acc = bl[o];
#pragma unroll 8
        for (int k = 0; k < HID; ++k) acc += p[k] * Wl[k * OUTF + o];
        out[g * OUTF + o] = acc;
    }
}

// ---------------- launch ----------------

extern "C" void kernel_launch(void* const* d_in, const int* in_sizes, int n_in,
                              void* d_out, int out_size, void* d_ws, size_t ws_size,
                              hipStream_t stream) {
    const float* x   = (const float*)d_in[0];
    const int*   ei  = (const int*)d_in[1];
    const int*   bat = (const int*)d_in[2];
    const float* W1  = (const float*)d_in[3];
    const float* b1  = (const float*)d_in[4];
    const float* W2  = (const float*)d_in[5];
    const float* b2  = (const float*)d_in[6];
    const float* W3  = (const float*)d_in[7];
    const float* b3  = (const float*)d_in[8];
    const float* Wl  = (const float*)d_in[9];
    const float* bl  = (const float*)d_in[10];

    const int N = in_sizes[0] / 10;
    const int E = in_sizes[1] / 2;
    const int G = out_size / OUTF;
    const int* src = ei;
    const int* dst = ei + E;

    // workspace layout (all 4-byte types; row_ptr padded to keep 16B alignment downstream)
    char* w = (char*)d_ws;
    float* bufA   = (float*)w; w += (size_t)N * HID * 4;
    float* bufB   = (float*)w; w += (size_t)N * HID * 4;
    float* dis    = (float*)w; w += (size_t)N * 4;
    int*   deg    = (int*)w;   w += (size_t)N * 4;
    int*   rowp   = (int*)w;   w += (size_t)(N + 8) * 4;
    int*   cursor = (int*)w;   w += (size_t)N * 4;
    int*   csrs   = (int*)w;   w += (size_t)E * 4;
    float* csrw   = (float*)w; w += (size_t)E * 4;
    float* sums   = (float*)w; w += (size_t)G * HID * 4;

    // --- gcn_norm + CSR build ---
    hipMemsetAsync(deg, 0, (size_t)N * 4, stream);
    deg_kernel<<<(E + 255) / 256, 256, 0, stream>>>(dst, E, deg);
    dis_kernel<<<(N + 255) / 256, 256, 0, stream>>>(deg, dis, N);
    scan_kernel<<<1, 1024, 0, stream>>>(deg, rowp, N);
    hipMemcpyAsync(cursor, rowp, (size_t)N * 4, hipMemcpyDeviceToDevice, stream);
    fill_csr_kernel<<<(E + 255) / 256, 256, 0, stream>>>(src, dst, E, dis, cursor, csrs, csrw);

    // --- layer 1 ---
    lin10_kernel<<<N, HID, 0, stream>>>(x, W1, bufA, N);
    aggregate_kernel<<<N, HID, 0, stream>>>(bufA, rowp, csrs, csrw, dis, b1, bufB, N, 1);
    // --- layer 2 ---
    lin128_kernel<8><<<(N + 7) / 8, HID, 0, stream>>>(bufB, W2, bufA, N);
    aggregate_kernel<<<N, HID, 0, stream>>>(bufA, rowp, csrs, csrw, dis, b2, bufB, N, 1);
    // --- layer 3 ---
    lin128_kernel<8><<<(N + 7) / 8, HID, 0, stream>>>(bufB, W3, bufA, N);
    aggregate_kernel<<<N, HID, 0, stream>>>(bufA, rowp, csrs, csrw, dis, b3, bufB, N, 0);

    // --- mean pool + head ---
    hipMemsetAsync(sums, 0, (size_t)G * HID * 4, stream);
    pool_kernel<<<dim3(G, 32), HID, 0, stream>>>(bufB, bat, N, sums);
    final_kernel<<<G, HID, 0, stream>>>(sums, bat, N, Wl, bl, (float*)d_out);
}

// Round 2
// 946.593 us; speedup vs baseline: 1.2181x; 1.2181x over previous
//
#include <hip/hip_runtime.h>
#include <hip/hip_bf16.h>

#define HID 128
#define OUTF 101
#define INF 10

typedef __hip_bfloat16 bf16;
typedef __hip_bfloat162 bf16x2;

__device__ __forceinline__ float blo(bf16x2 v) { return __bfloat162float(v.x); }
__device__ __forceinline__ float bhi(bf16x2 v) { return __bfloat162float(v.y); }
__device__ __forceinline__ bf16x2 mk2(float a, float b) {
    bf16x2 r; r.x = __float2bfloat16(a); r.y = __float2bfloat16(b); return r;
}

// ---------------- CSR build ----------------

__global__ void deg_kernel(const int* __restrict__ dst, int E, int* __restrict__ deg) {
    int e = blockIdx.x * blockDim.x + threadIdx.x;
    if (e < E) atomicAdd(&deg[dst[e]], 1);
}

__global__ void dis_kernel(const int* __restrict__ deg, float* __restrict__ dis, int n) {
    int i = blockIdx.x * blockDim.x + threadIdx.x;
    if (i < n) dis[i] = rsqrtf((float)(deg[i] + 1));  // +1 self-loop
}

__global__ __launch_bounds__(1024) void scan_kernel(const int* __restrict__ deg,
                                                    int* __restrict__ row_ptr, int n) {
    __shared__ int partial[1024];
    int tid = threadIdx.x;
    int chunk = (n + 1023) >> 10;
    int begin = tid * chunk;
    int end = begin + chunk;
    if (begin > n) begin = n;
    if (end > n) end = n;
    int sum = 0;
    for (int i = begin; i < end; ++i) sum += deg[i];
    partial[tid] = sum;
    __syncthreads();
    for (int off = 1; off < 1024; off <<= 1) {
        int v = 0;
        if (tid >= off) v = partial[tid - off];
        __syncthreads();
        if (tid >= off) partial[tid] += v;
        __syncthreads();
    }
    int prefix = (tid == 0) ? 0 : partial[tid - 1];
    for (int i = begin; i < end; ++i) {
        row_ptr[i] = prefix;
        prefix += deg[i];
    }
    if (tid == 1023) row_ptr[n] = partial[1023];
}

__global__ void fill_csr_kernel(const int* __restrict__ src, const int* __restrict__ dst, int E,
                                const float* __restrict__ dis, int* __restrict__ cursor,
                                int* __restrict__ csr_src, float* __restrict__ csr_w) {
    int e = blockIdx.x * blockDim.x + threadIdx.x;
    if (e >= E) return;
    int s = src[e];
    int d = dst[e];
    int pos = atomicAdd(&cursor[d], 1);
    csr_src[pos] = s;
    csr_w[pos] = dis[s] * dis[d];
}

// ---------------- layer 1: aggregate raw x (10 features), then transform ----------------

// ax[i][f] = dis[i]^2 * x[i][f] + sum_e w_e * x[src_e][f]
// 16 threads per node (10 active), 8 nodes per 128-block.
__global__ void agg10_kernel(const float* __restrict__ x, const int* __restrict__ row_ptr,
                             const int* __restrict__ csr_src, const float* __restrict__ csr_w,
                             const float* __restrict__ dis, float* __restrict__ ax, int n) {
    int t = threadIdx.x;
    int i = blockIdx.x * 8 + (t >> 4);
    int f = t & 15;
    if (i >= n || f >= INF) return;
    float di = dis[i];
    float acc = x[(size_t)i * INF + f] * (di * di);
    int beg = row_ptr[i];
    int end = row_ptr[i + 1];
    for (int e = beg; e < end; ++e) {
        int s = csr_src[e];
        float w = csr_w[e];
        acc += x[(size_t)s * INF + f] * w;
    }
    ax[(size_t)i * INF + f] = acc;
}

// h1 = relu(ax @ W1 + b1), written bf16. One block (128 thr) per node.
__global__ void lin10_kernel(const float* __restrict__ ax, const float* __restrict__ W,
                             const float* __restrict__ b, bf16* __restrict__ h, int n) {
    int i = blockIdx.x;
    int j = threadIdx.x;
    __shared__ float xs[INF];
    if (j < INF) xs[j] = ax[(size_t)i * INF + j];
    __syncthreads();
    float acc = b[j];
#pragma unroll
    for (int k = 0; k < INF; ++k) acc += xs[k] * W[k * HID + j];
    h[(size_t)i * HID + j] = __float2bfloat16(fmaxf(acc, 0.f));
}

// ---------------- dense 128x128 transform, bf16 in/out, fp32 math ----------------

template <int NB>
__global__ void lin128_kernel(const bf16* __restrict__ in, const float* __restrict__ W,
                              bf16* __restrict__ out, int n) {
    int j = threadIdx.x;
    int base = blockIdx.x * NB;
    __shared__ float xs[NB][HID];
#pragma unroll
    for (int m = 0; m < NB; ++m) {
        int i = base + m;
        xs[m][j] = (i < n) ? __bfloat162float(in[(size_t)i * HID + j]) : 0.f;
    }
    __syncthreads();
    float acc[NB];
#pragma unroll
    for (int m = 0; m < NB; ++m) acc[m] = 0.f;
    for (int k = 0; k < HID; ++k) {
        float wv = W[k * HID + j];
#pragma unroll
        for (int m = 0; m < NB; ++m) acc[m] += xs[m][k] * wv;
    }
#pragma unroll
    for (int m = 0; m < NB; ++m) {
        int i = base + m;
        if (i < n) out[(size_t)i * HID + j] = __float2bfloat16(acc[m]);
    }
}

// ---------------- aggregation over 128 bf16 features ----------------
// One wave (64 lanes) per node; lane handles 2 features via bf16x2 (4B) loads.
// Block = 256 threads = 4 nodes.
__global__ __launch_bounds__(256) void agg128_kernel(
        const bf16x2* __restrict__ h, const int* __restrict__ row_ptr,
        const int* __restrict__ csr_src, const float* __restrict__ csr_w,
        const float* __restrict__ dis, const float* __restrict__ b,
        bf16x2* __restrict__ out, int n, int relu) {
    int i = blockIdx.x * 4 + (threadIdx.x >> 6);
    int lane = threadIdx.x & 63;
    if (i >= n) return;
    float di = dis[i];
    bf16x2 sv = h[(size_t)i * 64 + lane];
    float w0 = di * di;
    float acc0 = blo(sv) * w0;
    float acc1 = bhi(sv) * w0;
    int beg = row_ptr[i];
    int end = row_ptr[i + 1];
    for (int e = beg; e < end; ++e) {
        int s = csr_src[e];
        float w = csr_w[e];
        bf16x2 v = h[(size_t)s * 64 + lane];
        acc0 += blo(v) * w;
        acc1 += bhi(v) * w;
    }
    acc0 += b[2 * lane];
    acc1 += b[2 * lane + 1];
    if (relu) { acc0 = fmaxf(acc0, 0.f); acc1 = fmaxf(acc1, 0.f); }
    out[(size_t)i * 64 + lane] = mk2(acc0, acc1);
}

// ---------------- pooling + head ----------------

__global__ void pool_kernel(const bf16* __restrict__ h, const int* __restrict__ batch, int n,
                            float* __restrict__ sums) {
    int g = blockIdx.x;
    int j = threadIdx.x;
    int lo = 0, hi = n;
    while (lo < hi) { int mid = (lo + hi) >> 1; if (batch[mid] < g) lo = mid + 1; else hi = mid; }
    int start = lo;
    lo = start; hi = n;
    while (lo < hi) { int mid = (lo + hi) >> 1; if (batch[mid] < g + 1) lo = mid + 1; else hi = mid; }
    int end = lo;
    float acc = 0.f;
    for (int i = start + blockIdx.y; i < end; i += gridDim.y)
        acc += __bfloat162float(h[(size_t)i * HID + j]);
    atomicAdd(&sums[g * HID + j], acc);
}

__global__ void final_kernel(const float* __restrict__ sums, const int* __restrict__ batch, int n,
                             const float* __restrict__ Wl, const float* __restrict__ bl,
                             float* __restrict__ out) {
    int g = blockIdx.x;
    int o = threadIdx.x;
    __shared__ float p[HID];
    int lo = 0, hi = n;
    while (lo < hi) { int mid = (lo + hi) >> 1; if (batch[mid] < g) lo = mid + 1; else hi = mid; }
    int start = lo;
    lo = start; hi = n;
    while (lo < hi) { int mid = (lo + hi) >> 1; if (batch[mid] < g + 1) lo = mid + 1; else hi = mid; }
    float cnt = fmaxf((float)(lo - start), 1.0f);
    p[o] = sums[g * HID + o] / cnt;
    __syncthreads();
    if (o < OUTF) {
        float acc = bl[o];
#pragma unroll 8
        for (int k = 0; k < HID; ++k) acc += p[k] * Wl[k * OUTF + o];
        out[g * OUTF + o] = acc;
    }
}

// ---------------- launch ----------------

extern "C" void kernel_launch(void* const* d_in, const int* in_sizes, int n_in,
                              void* d_out, int out_size, void* d_ws, size_t ws_size,
                              hipStream_t stream) {
    const float* x   = (const float*)d_in[0];
    const int*   ei  = (const int*)d_in[1];
    const int*   bat = (const int*)d_in[2];
    const float* W1  = (const float*)d_in[3];
    const float* b1  = (const float*)d_in[4];
    const float* W2  = (const float*)d_in[5];
    const float* b2  = (const float*)d_in[6];
    const float* W3  = (const float*)d_in[7];
    const float* b3  = (const float*)d_in[8];
    const float* Wl  = (const float*)d_in[9];
    const float* bl  = (const float*)d_in[10];

    const int N = in_sizes[0] / INF;
    const int E = in_sizes[1] / 2;
    const int G = out_size / OUTF;
    const int* src = ei;
    const int* dst = ei + E;

    char* w = (char*)d_ws;
    bf16*  bufA   = (bf16*)w;  w += (size_t)N * HID * 2;   // 25.6 MB
    bf16*  bufB   = (bf16*)w;  w += (size_t)N * HID * 2;   // 25.6 MB
    float* ax     = (float*)w; w += (size_t)N * INF * 4;   // 4 MB
    float* dis    = (float*)w; w += (size_t)N * 4;
    int*   deg    = (int*)w;   w += (size_t)N * 4;
    int*   rowp   = (int*)w;   w += (size_t)(N + 8) * 4;
    int*   cursor = (int*)w;   w += (size_t)N * 4;
    int*   csrs   = (int*)w;   w += (size_t)E * 4;
    float* csrw   = (float*)w; w += (size_t)E * 4;
    float* sums   = (float*)w; w += (size_t)G * HID * 4;

    // --- gcn_norm + CSR build ---
    hipMemsetAsync(deg, 0, (size_t)N * 4, stream);
    deg_kernel<<<(E + 255) / 256, 256, 0, stream>>>(dst, E, deg);
    dis_kernel<<<(N + 255) / 256, 256, 0, stream>>>(deg, dis, N);
    scan_kernel<<<1, 1024, 0, stream>>>(deg, rowp, N);
    hipMemcpyAsync(cursor, rowp, (size_t)N * 4, hipMemcpyDeviceToDevice, stream);
    fill_csr_kernel<<<(E + 255) / 256, 256, 0, stream>>>(src, dst, E, dis, cursor, csrs, csrw);

    // --- layer 1: (A x) W1 ---
    agg10_kernel<<<(N + 7) / 8, 128, 0, stream>>>(x, rowp, csrs, csrw, dis, ax, N);
    lin10_kernel<<<N, HID, 0, stream>>>(ax, W1, b1, bufA, N);
    // --- layer 2 ---
    lin128_kernel<8><<<(N + 7) / 8, HID, 0, stream>>>(bufA, W2, bufB, N);
    agg128_kernel<<<(N + 3) / 4, 256, 0, stream>>>((const bf16x2*)bufB, rowp, csrs, csrw, dis, b2,
                                                   (bf16x2*)bufA, N, 1);
    // --- layer 3 ---
    lin128_kernel<8><<<(N + 7) / 8, HID, 0, stream>>>(bufA, W3, bufB, N);
    agg128_kernel<<<(N + 3) / 4, 256, 0, stream>>>((const bf16x2*)bufB, rowp, csrs, csrw, dis, b3,
                                                   (bf16x2*)bufA, N, 0);

    // --- mean pool + head ---
    hipMemsetAsync(sums, 0, (size_t)G * HID * 4, stream);
    pool_kernel<<<dim3(G, 32), HID, 0, stream>>>(bufA, bat, N, sums);
    final_kernel<<<G, HID, 0, stream>>>(sums, bat, N, Wl, bl, (float*)d_out);
}

// Round 3
// 638.353 us; speedup vs baseline: 1.8063x; 1.4829x over previous
//
#include <hip/hip_runtime.h>
#include <hip/hip_bf16.h>

#define HID 128
#define OUTF 101
#define INF 10

#define SCAN_TPB 256
#define SCAN_EPT 4
#define SCAN_EPB (SCAN_TPB * SCAN_EPT)  // 1024 elements per block

typedef __hip_bfloat16 bf16;
typedef __hip_bfloat162 bf16x2;

__device__ __forceinline__ float blo(bf16x2 v) { return __bfloat162float(v.x); }
__device__ __forceinline__ float bhi(bf16x2 v) { return __bfloat162float(v.y); }
__device__ __forceinline__ bf16x2 mk2(float a, float b) {
    bf16x2 r; r.x = __float2bfloat16(a); r.y = __float2bfloat16(b); return r;
}

// ---------------- CSR build ----------------

__global__ void deg_kernel(const int* __restrict__ dst, int E, int* __restrict__ deg) {
    int e = blockIdx.x * blockDim.x + threadIdx.x;
    if (e < E) atomicAdd(&deg[dst[e]], 1);
}

// Phase 1: per-block sum of deg; also compute dis = rsqrt(deg+1) (fused).
__global__ __launch_bounds__(SCAN_TPB) void scan1_kernel(const int* __restrict__ deg,
                                                         float* __restrict__ dis,
                                                         int* __restrict__ blocksum, int n) {
    int base = blockIdx.x * SCAN_EPB + threadIdx.x * SCAN_EPT;
    int s = 0;
#pragma unroll
    for (int t = 0; t < SCAN_EPT; ++t) {
        int i = base + t;
        if (i < n) {
            int d = deg[i];
            s += d;
            dis[i] = rsqrtf((float)(d + 1));
        }
    }
    __shared__ int red[SCAN_TPB];
    red[threadIdx.x] = s;
    __syncthreads();
    for (int off = SCAN_TPB / 2; off > 0; off >>= 1) {
        if (threadIdx.x < off) red[threadIdx.x] += red[threadIdx.x + off];
        __syncthreads();
    }
    if (threadIdx.x == 0) blocksum[blockIdx.x] = red[0];
}

// Phase 2: single block turns blocksum[] into exclusive block offsets (nb <= 256).
__global__ __launch_bounds__(SCAN_TPB) void scan2_kernel(int* __restrict__ blocksum, int nb) {
    __shared__ int sh[SCAN_TPB];
    int tid = threadIdx.x;
    sh[tid] = (tid < nb) ? blocksum[tid] : 0;
    __syncthreads();
    for (int off = 1; off < SCAN_TPB; off <<= 1) {
        int t = (tid >= off) ? sh[tid - off] : 0;
        __syncthreads();
        sh[tid] += t;
        __syncthreads();
    }
    if (tid < nb) blocksum[tid] = (tid == 0) ? 0 : sh[tid - 1];
}

// Phase 3: block-local exclusive scan + block offset -> row_ptr and cursor.
__global__ __launch_bounds__(SCAN_TPB) void scan3_kernel(const int* __restrict__ deg,
                                                         const int* __restrict__ blockoff,
                                                         int* __restrict__ row_ptr,
                                                         int* __restrict__ cursor, int n) {
    int tid = threadIdx.x;
    int base = blockIdx.x * SCAN_EPB + tid * SCAN_EPT;
    int vals[SCAN_EPT];
    int s = 0;
#pragma unroll
    for (int t = 0; t < SCAN_EPT; ++t) {
        int i = base + t;
        vals[t] = (i < n) ? deg[i] : 0;
        s += vals[t];
    }
    __shared__ int sh[SCAN_TPB];
    sh[tid] = s;
    __syncthreads();
    for (int off = 1; off < SCAN_TPB; off <<= 1) {
        int t = (tid >= off) ? sh[tid - off] : 0;
        __syncthreads();
        sh[tid] += t;
        __syncthreads();
    }
    int off = blockoff[blockIdx.x] + ((tid == 0) ? 0 : sh[tid - 1]);
#pragma unroll
    for (int t = 0; t < SCAN_EPT; ++t) {
        int i = base + t;
        if (i < n) {
            row_ptr[i] = off;
            cursor[i] = off;
            off += vals[t];
        } else if (i == n) {
            row_ptr[n] = off;  // total E
        }
    }
}

__global__ void fill_csr_kernel(const int* __restrict__ src, const int* __restrict__ dst, int E,
                                const float* __restrict__ dis, int* __restrict__ cursor,
                                int* __restrict__ csr_src, float* __restrict__ csr_w) {
    int e = blockIdx.x * blockDim.x + threadIdx.x;
    if (e >= E) return;
    int s = src[e];
    int d = dst[e];
    int pos = atomicAdd(&cursor[d], 1);
    csr_src[pos] = s;
    csr_w[pos] = dis[s] * dis[d];
}

// ---------------- layer 1: aggregate raw x (10 features), then transform ----------------

__global__ void agg10_kernel(const float* __restrict__ x, const int* __restrict__ row_ptr,
                             const int* __restrict__ csr_src, const float* __restrict__ csr_w,
                             const float* __restrict__ dis, float* __restrict__ ax, int n) {
    int t = threadIdx.x;
    int i = blockIdx.x * 8 + (t >> 4);
    int f = t & 15;
    if (i >= n || f >= INF) return;
    float di = dis[i];
    float acc = x[(size_t)i * INF + f] * (di * di);
    int beg = row_ptr[i];
    int end = row_ptr[i + 1];
    for (int e = beg; e < end; ++e) {
        int s = csr_src[e];
        float w = csr_w[e];
        acc += x[(size_t)s * INF + f] * w;
    }
    ax[(size_t)i * INF + f] = acc;
}

__global__ void lin10_kernel(const float* __restrict__ ax, const float* __restrict__ W,
                             const float* __restrict__ b, bf16* __restrict__ h, int n) {
    int i = blockIdx.x;
    int j = threadIdx.x;
    __shared__ float xs[INF];
    if (j < INF) xs[j] = ax[(size_t)i * INF + j];
    __syncthreads();
    float acc = b[j];
#pragma unroll
    for (int k = 0; k < INF; ++k) acc += xs[k] * W[k * HID + j];
    h[(size_t)i * HID + j] = __float2bfloat16(fmaxf(acc, 0.f));
}

// ---------------- dense 128x128 transform, bf16 in/out, fp32 math ----------------

template <int NB>
__global__ void lin128_kernel(const bf16* __restrict__ in, const float* __restrict__ W,
                              bf16* __restrict__ out, int n) {
    int j = threadIdx.x;
    int base = blockIdx.x * NB;
    __shared__ float xs[NB][HID];
#pragma unroll
    for (int m = 0; m < NB; ++m) {
        int i = base + m;
        xs[m][j] = (i < n) ? __bfloat162float(in[(size_t)i * HID + j]) : 0.f;
    }
    __syncthreads();
    float acc[NB];
#pragma unroll
    for (int m = 0; m < NB; ++m) acc[m] = 0.f;
    for (int k = 0; k < HID; k += 4) {
        float w0 = W[(k + 0) * HID + j];
        float w1 = W[(k + 1) * HID + j];
        float w2 = W[(k + 2) * HID + j];
        float w3 = W[(k + 3) * HID + j];
#pragma unroll
        for (int m = 0; m < NB; ++m) {
            float4 xv = *(const float4*)&xs[m][k];
            acc[m] = fmaf(xv.x, w0, acc[m]);
            acc[m] = fmaf(xv.y, w1, acc[m]);
            acc[m] = fmaf(xv.z, w2, acc[m]);
            acc[m] = fmaf(xv.w, w3, acc[m]);
        }
    }
#pragma unroll
    for (int m = 0; m < NB; ++m) {
        int i = base + m;
        if (i < n) out[(size_t)i * HID + j] = __float2bfloat16(acc[m]);
    }
}

// ---------------- aggregation over 128 bf16 features ----------------
// One wave per node; lane handles 2 features (bf16x2). 4x unrolled edge loop for MLP.
__global__ __launch_bounds__(256) void agg128_kernel(
        const bf16x2* __restrict__ h, const int* __restrict__ row_ptr,
        const int* __restrict__ csr_src, const float* __restrict__ csr_w,
        const float* __restrict__ dis, const float* __restrict__ b,
        bf16x2* __restrict__ out, int n, int relu) {
    int i = blockIdx.x * 4 + (threadIdx.x >> 6);
    int lane = threadIdx.x & 63;
    if (i >= n) return;
    float di = dis[i];
    bf16x2 sv = h[(size_t)i * 64 + lane];
    float wself = di * di;
    float acc0 = blo(sv) * wself;
    float acc1 = bhi(sv) * wself;
    int beg = row_ptr[i];
    int end = row_ptr[i + 1];
    int e = beg;
    for (; e + 4 <= end; e += 4) {
        int s0 = csr_src[e + 0], s1 = csr_src[e + 1], s2 = csr_src[e + 2], s3 = csr_src[e + 3];
        float w0 = csr_w[e + 0], w1 = csr_w[e + 1], w2 = csr_w[e + 2], w3 = csr_w[e + 3];
        bf16x2 v0 = h[(size_t)s0 * 64 + lane];
        bf16x2 v1 = h[(size_t)s1 * 64 + lane];
        bf16x2 v2 = h[(size_t)s2 * 64 + lane];
        bf16x2 v3 = h[(size_t)s3 * 64 + lane];
        acc0 += blo(v0) * w0; acc1 += bhi(v0) * w0;
        acc0 += blo(v1) * w1; acc1 += bhi(v1) * w1;
        acc0 += blo(v2) * w2; acc1 += bhi(v2) * w2;
        acc0 += blo(v3) * w3; acc1 += bhi(v3) * w3;
    }
    for (; e < end; ++e) {
        int s = csr_src[e];
        float w = csr_w[e];
        bf16x2 v = h[(size_t)s * 64 + lane];
        acc0 += blo(v) * w;
        acc1 += bhi(v) * w;
    }
    acc0 += b[2 * lane];
    acc1 += b[2 * lane + 1];
    if (relu) { acc0 = fmaxf(acc0, 0.f); acc1 = fmaxf(acc1, 0.f); }
    out[(size_t)i * 64 + lane] = mk2(acc0, acc1);
}

// ---------------- pooling + head ----------------

__global__ void pool_kernel(const bf16* __restrict__ h, const int* __restrict__ batch, int n,
                            float* __restrict__ sums) {
    int g = blockIdx.x;
    int j = threadIdx.x;
    int lo = 0, hi = n;
    while (lo < hi) { int mid = (lo + hi) >> 1; if (batch[mid] < g) lo = mid + 1; else hi = mid; }
    int start = lo;
    lo = start; hi = n;
    while (lo < hi) { int mid = (lo + hi) >> 1; if (batch[mid] < g + 1) lo = mid + 1; else hi = mid; }
    int end = lo;
    float acc = 0.f;
    for (int i = start + blockIdx.y; i < end; i += gridDim.y)
        acc += __bfloat162float(h[(size_t)i * HID + j]);
    atomicAdd(&sums[g * HID + j], acc);
}

__global__ void final_kernel(const float* __restrict__ sums, const int* __restrict__ batch, int n,
                             const float* __restrict__ Wl, const float* __restrict__ bl,
                             float* __restrict__ out) {
    int g = blockIdx.x;
    int o = threadIdx.x;
    __shared__ float p[HID];
    int lo = 0, hi = n;
    while (lo < hi) { int mid = (lo + hi) >> 1; if (batch[mid] < g) lo = mid + 1; else hi = mid; }
    int start = lo;
    lo = start; hi = n;
    while (lo < hi) { int mid = (lo + hi) >> 1; if (batch[mid] < g + 1) lo = mid + 1; else hi = mid; }
    float cnt = fmaxf((float)(lo - start), 1.0f);
    p[o] = sums[g * HID + o] / cnt;
    __syncthreads();
    if (o < OUTF) {
        float acc = bl[o];
#pragma unroll 8
        for (int k = 0; k < HID; ++k) acc += p[k] * Wl[k * OUTF + o];
        out[g * OUTF + o] = acc;
    }
}

// ---------------- launch ----------------

extern "C" void kernel_launch(void* const* d_in, const int* in_sizes, int n_in,
                              void* d_out, int out_size, void* d_ws, size_t ws_size,
                              hipStream_t stream) {
    const float* x   = (const float*)d_in[0];
    const int*   ei  = (const int*)d_in[1];
    const int*   bat = (const int*)d_in[2];
    const float* W1  = (const float*)d_in[3];
    const float* b1  = (const float*)d_in[4];
    const float* W2  = (const float*)d_in[5];
    const float* b2  = (const float*)d_in[6];
    const float* W3  = (const float*)d_in[7];
    const float* b3  = (const float*)d_in[8];
    const float* Wl  = (const float*)d_in[9];
    const float* bl  = (const float*)d_in[10];

    const int N = in_sizes[0] / INF;
    const int E = in_sizes[1] / 2;
    const int G = out_size / OUTF;
    const int* src = ei;
    const int* dst = ei + E;

    const int nb = N / SCAN_EPB + 1;  // covers index N for row_ptr[N]; nb <= 256 required

    char* w = (char*)d_ws;
    bf16*  bufA   = (bf16*)w;  w += (size_t)N * HID * 2;
    bf16*  bufB   = (bf16*)w;  w += (size_t)N * HID * 2;
    float* ax     = (float*)w; w += (size_t)N * INF * 4;
    float* dis    = (float*)w; w += (size_t)N * 4;
    int*   deg    = (int*)w;   w += (size_t)N * 4;
    int*   rowp   = (int*)w;   w += (size_t)(N + 8) * 4;
    int*   cursor = (int*)w;   w += (size_t)N * 4;
    int*   csrs   = (int*)w;   w += (size_t)E * 4;
    float* csrw   = (float*)w; w += (size_t)E * 4;
    float* sums   = (float*)w; w += (size_t)G * HID * 4;
    int*   bsum   = (int*)w;   w += (size_t)(nb + 8) * 4;

    // --- gcn_norm + CSR build ---
    hipMemsetAsync(deg, 0, (size_t)N * 4, stream);
    deg_kernel<<<(E + 255) / 256, 256, 0, stream>>>(dst, E, deg);
    scan1_kernel<<<nb, SCAN_TPB, 0, stream>>>(deg, dis, bsum, N);
    scan2_kernel<<<1, SCAN_TPB, 0, stream>>>(bsum, nb);
    scan3_kernel<<<nb, SCAN_TPB, 0, stream>>>(deg, bsum, rowp, cursor, N);
    fill_csr_kernel<<<(E + 255) / 256, 256, 0, stream>>>(src, dst, E, dis, cursor, csrs, csrw);

    // --- layer 1: (A x) W1 ---
    agg10_kernel<<<(N + 7) / 8, 128, 0, stream>>>(x, rowp, csrs, csrw, dis, ax, N);
    lin10_kernel<<<N, HID, 0, stream>>>(ax, W1, b1, bufA, N);
    // --- layer 2 ---
    lin128_kernel<8><<<(N + 7) / 8, HID, 0, stream>>>(bufA, W2, bufB, N);
    agg128_kernel<<<(N + 3) / 4, 256, 0, stream>>>((const bf16x2*)bufB, rowp, csrs, csrw, dis, b2,
                                                   (bf16x2*)bufA, N, 1);
    // --- layer 3 ---
    lin128_kernel<8><<<(N + 7) / 8, HID, 0, stream>>>(bufA, W3, bufB, N);
    agg128_kernel<<<(N + 3) / 4, 256, 0, stream>>>((const bf16x2*)bufB, rowp, csrs, csrw, dis, b3,
                                                   (bf16x2*)bufA, N, 0);

    // --- mean pool + head ---
    hipMemsetAsync(sums, 0, (size_t)G * HID * 4, stream);
    pool_kernel<<<dim3(G, 32), HID, 0, stream>>>(bufA, bat, N, sums);
    final_kernel<<<G, HID, 0, stream>>>(sums, bat, N, Wl, bl, (float*)d_out);
}

// Round 4
// 619.522 us; speedup vs baseline: 1.8612x; 1.0304x over previous
//
#include <hip/hip_runtime.h>
#include <hip/hip_bf16.h>

#define HID 128
#define OUTF 101
#define INF 10

#define SCAN_TPB 256
#define SCAN_EPT 4
#define SCAN_EPB (SCAN_TPB * SCAN_EPT)  // 1024 elements per block

typedef __hip_bfloat16 bf16;
typedef __hip_bfloat162 bf16x2;

__device__ __forceinline__ float blo(bf16x2 v) { return __bfloat162float(v.x); }
__device__ __forceinline__ float bhi(bf16x2 v) { return __bfloat162float(v.y); }
__device__ __forceinline__ bf16x2 mk2(float a, float b) {
    bf16x2 r; r.x = __float2bfloat16(a); r.y = __float2bfloat16(b); return r;
}

// ---------------- CSR build ----------------

__global__ void deg_kernel(const int* __restrict__ dst, int E, int* __restrict__ deg) {
    int e = blockIdx.x * blockDim.x + threadIdx.x;
    if (e < E) atomicAdd(&deg[dst[e]], 1);
}

// Phase 1: per-block sum of deg; also compute dis = rsqrt(deg+1) (fused).
__global__ __launch_bounds__(SCAN_TPB) void scan1_kernel(const int* __restrict__ deg,
                                                         float* __restrict__ dis,
                                                         int* __restrict__ blocksum, int n) {
    int base = blockIdx.x * SCAN_EPB + threadIdx.x * SCAN_EPT;
    int s = 0;
#pragma unroll
    for (int t = 0; t < SCAN_EPT; ++t) {
        int i = base + t;
        if (i < n) {
            int d = deg[i];
            s += d;
            dis[i] = rsqrtf((float)(d + 1));
        }
    }
    __shared__ int red[SCAN_TPB];
    red[threadIdx.x] = s;
    __syncthreads();
    for (int off = SCAN_TPB / 2; off > 0; off >>= 1) {
        if (threadIdx.x < off) red[threadIdx.x] += red[threadIdx.x + off];
        __syncthreads();
    }
    if (threadIdx.x == 0) blocksum[blockIdx.x] = red[0];
}

// Phase 2: single block turns blocksum[] into exclusive block offsets (nb <= 256).
__global__ __launch_bounds__(SCAN_TPB) void scan2_kernel(int* __restrict__ blocksum, int nb) {
    __shared__ int sh[SCAN_TPB];
    int tid = threadIdx.x;
    sh[tid] = (tid < nb) ? blocksum[tid] : 0;
    __syncthreads();
    for (int off = 1; off < SCAN_TPB; off <<= 1) {
        int t = (tid >= off) ? sh[tid - off] : 0;
        __syncthreads();
        sh[tid] += t;
        __syncthreads();
    }
    if (tid < nb) blocksum[tid] = (tid == 0) ? 0 : sh[tid - 1];
}

// Phase 3: block-local exclusive scan + block offset -> row_ptr and cursor.
__global__ __launch_bounds__(SCAN_TPB) void scan3_kernel(const int* __restrict__ deg,
                                                         const int* __restrict__ blockoff,
                                                         int* __restrict__ row_ptr,
                                                         int* __restrict__ cursor, int n) {
    int tid = threadIdx.x;
    int base = blockIdx.x * SCAN_EPB + tid * SCAN_EPT;
    int vals[SCAN_EPT];
    int s = 0;
#pragma unroll
    for (int t = 0; t < SCAN_EPT; ++t) {
        int i = base + t;
        vals[t] = (i < n) ? deg[i] : 0;
        s += vals[t];
    }
    __shared__ int sh[SCAN_TPB];
    sh[tid] = s;
    __syncthreads();
    for (int off = 1; off < SCAN_TPB; off <<= 1) {
        int t = (tid >= off) ? sh[tid - off] : 0;
        __syncthreads();
        sh[tid] += t;
        __syncthreads();
    }
    int off = blockoff[blockIdx.x] + ((tid == 0) ? 0 : sh[tid - 1]);
#pragma unroll
    for (int t = 0; t < SCAN_EPT; ++t) {
        int i = base + t;
        if (i < n) {
            row_ptr[i] = off;
            cursor[i] = off;
            off += vals[t];
        } else if (i == n) {
            row_ptr[n] = off;  // total E
        }
    }
}

// Packed CSR entry: .x = src node, .y = edge weight bits. ONE 8B scattered store
// per edge (was two 4B stores to two arrays -> 2 dirty lines; this halves
// write-allocate traffic, the round-3 bottleneck: WRITE_SIZE 155MB for 12.8MB payload).
__global__ void fill_csr_kernel(const int* __restrict__ src, const int* __restrict__ dst, int E,
                                const float* __restrict__ dis, int* __restrict__ cursor,
                                int2* __restrict__ csr) {
    int e = blockIdx.x * blockDim.x + threadIdx.x;
    if (e >= E) return;
    int s = src[e];
    int d = dst[e];
    int pos = atomicAdd(&cursor[d], 1);
    int2 ent;
    ent.x = s;
    ent.y = __float_as_int(dis[s] * dis[d]);
    csr[pos] = ent;
}

// ---------------- layer 1: aggregate raw x (10 features), then transform ----------------

__global__ void agg10_kernel(const float* __restrict__ x, const int* __restrict__ row_ptr,
                             const int2* __restrict__ csr,
                             const float* __restrict__ dis, float* __restrict__ ax, int n) {
    int t = threadIdx.x;
    int i = blockIdx.x * 8 + (t >> 4);
    int f = t & 15;
    if (i >= n || f >= INF) return;
    float di = dis[i];
    float acc = x[(size_t)i * INF + f] * (di * di);
    int beg = row_ptr[i];
    int end = row_ptr[i + 1];
    for (int e = beg; e < end; ++e) {
        int2 p = csr[e];
        acc += x[(size_t)p.x * INF + f] * __int_as_float(p.y);
    }
    ax[(size_t)i * INF + f] = acc;
}

__global__ void lin10_kernel(const float* __restrict__ ax, const float* __restrict__ W,
                             const float* __restrict__ b, bf16* __restrict__ h, int n) {
    int i = blockIdx.x;
    int j = threadIdx.x;
    __shared__ float xs[INF];
    if (j < INF) xs[j] = ax[(size_t)i * INF + j];
    __syncthreads();
    float acc = b[j];
#pragma unroll
    for (int k = 0; k < INF; ++k) acc += xs[k] * W[k * HID + j];
    h[(size_t)i * HID + j] = __float2bfloat16(fmaxf(acc, 0.f));
}

// ---------------- dense 128x128 transform, bf16 in/out, fp32 math ----------------

template <int NB>
__global__ void lin128_kernel(const bf16* __restrict__ in, const float* __restrict__ W,
                              bf16* __restrict__ out, int n) {
    int j = threadIdx.x;
    int base = blockIdx.x * NB;
    __shared__ float xs[NB][HID];
#pragma unroll
    for (int m = 0; m < NB; ++m) {
        int i = base + m;
        xs[m][j] = (i < n) ? __bfloat162float(in[(size_t)i * HID + j]) : 0.f;
    }
    __syncthreads();
    float acc[NB];
#pragma unroll
    for (int m = 0; m < NB; ++m) acc[m] = 0.f;
    for (int k = 0; k < HID; k += 4) {
        float w0 = W[(k + 0) * HID + j];
        float w1 = W[(k + 1) * HID + j];
        float w2 = W[(k + 2) * HID + j];
        float w3 = W[(k + 3) * HID + j];
#pragma unroll
        for (int m = 0; m < NB; ++m) {
            float4 xv = *(const float4*)&xs[m][k];
            acc[m] = fmaf(xv.x, w0, acc[m]);
            acc[m] = fmaf(xv.y, w1, acc[m]);
            acc[m] = fmaf(xv.z, w2, acc[m]);
            acc[m] = fmaf(xv.w, w3, acc[m]);
        }
    }
#pragma unroll
    for (int m = 0; m < NB; ++m) {
        int i = base + m;
        if (i < n) out[(size_t)i * HID + j] = __float2bfloat16(acc[m]);
    }
}

// ---------------- aggregation over 128 bf16 features ----------------
// One wave per node; lane handles 2 features (bf16x2). 4x unrolled edge loop for MLP.
__global__ __launch_bounds__(256) void agg128_kernel(
        const bf16x2* __restrict__ h, const int* __restrict__ row_ptr,
        const int2* __restrict__ csr,
        const float* __restrict__ dis, const float* __restrict__ b,
        bf16x2* __restrict__ out, int n, int relu) {
    int i = blockIdx.x * 4 + (threadIdx.x >> 6);
    int lane = threadIdx.x & 63;
    if (i >= n) return;
    float di = dis[i];
    bf16x2 sv = h[(size_t)i * 64 + lane];
    float wself = di * di;
    float acc0 = blo(sv) * wself;
    float acc1 = bhi(sv) * wself;
    int beg = row_ptr[i];
    int end = row_ptr[i + 1];
    int e = beg;
    for (; e + 4 <= end; e += 4) {
        int2 p0 = csr[e + 0], p1 = csr[e + 1], p2 = csr[e + 2], p3 = csr[e + 3];
        bf16x2 v0 = h[(size_t)p0.x * 64 + lane];
        bf16x2 v1 = h[(size_t)p1.x * 64 + lane];
        bf16x2 v2 = h[(size_t)p2.x * 64 + lane];
        bf16x2 v3 = h[(size_t)p3.x * 64 + lane];
        float w0 = __int_as_float(p0.y), w1 = __int_as_float(p1.y);
        float w2 = __int_as_float(p2.y), w3 = __int_as_float(p3.y);
        acc0 += blo(v0) * w0; acc1 += bhi(v0) * w0;
        acc0 += blo(v1) * w1; acc1 += bhi(v1) * w1;
        acc0 += blo(v2) * w2; acc1 += bhi(v2) * w2;
        acc0 += blo(v3) * w3; acc1 += bhi(v3) * w3;
    }
    for (; e < end; ++e) {
        int2 p = csr[e];
        float w = __int_as_float(p.y);
        bf16x2 v = h[(size_t)p.x * 64 + lane];
        acc0 += blo(v) * w;
        acc1 += bhi(v) * w;
    }
    acc0 += b[2 * lane];
    acc1 += b[2 * lane + 1];
    if (relu) { acc0 = fmaxf(acc0, 0.f); acc1 = fmaxf(acc1, 0.f); }
    out[(size_t)i * 64 + lane] = mk2(acc0, acc1);
}

// ---------------- pooling + head ----------------

__global__ void pool_kernel(const bf16* __restrict__ h, const int* __restrict__ batch, int n,
                            float* __restrict__ sums) {
    int g = blockIdx.x;
    int j = threadIdx.x;
    int lo = 0, hi = n;
    while (lo < hi) { int mid = (lo + hi) >> 1; if (batch[mid] < g) lo = mid + 1; else hi = mid; }
    int start = lo;
    lo = start; hi = n;
    while (lo < hi) { int mid = (lo + hi) >> 1; if (batch[mid] < g + 1) lo = mid + 1; else hi = mid; }
    int end = lo;
    float acc = 0.f;
    for (int i = start + blockIdx.y; i < end; i += gridDim.y)
        acc += __bfloat162float(h[(size_t)i * HID + j]);
    atomicAdd(&sums[g * HID + j], acc);
}

__global__ void final_kernel(const float* __restrict__ sums, const int* __restrict__ batch, int n,
                             const float* __restrict__ Wl, const float* __restrict__ bl,
                             float* __restrict__ out) {
    int g = blockIdx.x;
    int o = threadIdx.x;
    __shared__ float p[HID];
    int lo = 0, hi = n;
    while (lo < hi) { int mid = (lo + hi) >> 1; if (batch[mid] < g) lo = mid + 1; else hi = mid; }
    int start = lo;
    lo = start; hi = n;
    while (lo < hi) { int mid = (lo + hi) >> 1; if (batch[mid] < g + 1) lo = mid + 1; else hi = mid; }
    float cnt = fmaxf((float)(lo - start), 1.0f);
    p[o] = sums[g * HID + o] / cnt;
    __syncthreads();
    if (o < OUTF) {
        float acc = bl[o];
#pragma unroll 8
        for (int k = 0; k < HID; ++k) acc += p[k] * Wl[k * OUTF + o];
        out[g * OUTF + o] = acc;
    }
}

// ---------------- launch ----------------

extern "C" void kernel_launch(void* const* d_in, const int* in_sizes, int n_in,
                              void* d_out, int out_size, void* d_ws, size_t ws_size,
                              hipStream_t stream) {
    const float* x   = (const float*)d_in[0];
    const int*   ei  = (const int*)d_in[1];
    const int*   bat = (const int*)d_in[2];
    const float* W1  = (const float*)d_in[3];
    const float* b1  = (const float*)d_in[4];
    const float* W2  = (const float*)d_in[5];
    const float* b2  = (const float*)d_in[6];
    const float* W3  = (const float*)d_in[7];
    const float* b3  = (const float*)d_in[8];
    const float* Wl  = (const float*)d_in[9];
    const float* bl  = (const float*)d_in[10];

    const int N = in_sizes[0] / INF;
    const int E = in_sizes[1] / 2;
    const int G = out_size / OUTF;
    const int* src = ei;
    const int* dst = ei + E;

    const int nb = N / SCAN_EPB + 1;  // covers index N for row_ptr[N]; nb <= 256 required

    char* w = (char*)d_ws;
    bf16*  bufA   = (bf16*)w;  w += (size_t)N * HID * 2;
    bf16*  bufB   = (bf16*)w;  w += (size_t)N * HID * 2;
    float* ax     = (float*)w; w += (size_t)N * INF * 4;
    float* dis    = (float*)w; w += (size_t)N * 4;
    int*   deg    = (int*)w;   w += (size_t)N * 4;
    int*   rowp   = (int*)w;   w += (size_t)(N + 8) * 4;
    int*   cursor = (int*)w;   w += (size_t)N * 4;
    int2*  csr    = (int2*)w;  w += (size_t)E * 8;
    float* sums   = (float*)w; w += (size_t)G * HID * 4;
    int*   bsum   = (int*)w;   w += (size_t)(nb + 8) * 4;

    // --- gcn_norm + CSR build ---
    hipMemsetAsync(deg, 0, (size_t)N * 4, stream);
    deg_kernel<<<(E + 255) / 256, 256, 0, stream>>>(dst, E, deg);
    scan1_kernel<<<nb, SCAN_TPB, 0, stream>>>(deg, dis, bsum, N);
    scan2_kernel<<<1, SCAN_TPB, 0, stream>>>(bsum, nb);
    scan3_kernel<<<nb, SCAN_TPB, 0, stream>>>(deg, bsum, rowp, cursor, N);
    fill_csr_kernel<<<(E + 255) / 256, 256, 0, stream>>>(src, dst, E, dis, cursor, csr);

    // --- layer 1: (A x) W1 ---
    agg10_kernel<<<(N + 7) / 8, 128, 0, stream>>>(x, rowp, csr, dis, ax, N);
    lin10_kernel<<<N, HID, 0, stream>>>(ax, W1, b1, bufA, N);
    // --- layer 2 ---
    lin128_kernel<8><<<(N + 7) / 8, HID, 0, stream>>>(bufA, W2, bufB, N);
    agg128_kernel<<<(N + 3) / 4, 256, 0, stream>>>((const bf16x2*)bufB, rowp, csr, dis, b2,
                                                   (bf16x2*)bufA, N, 1);
    // --- layer 3 ---
    lin128_kernel<8><<<(N + 7) / 8, HID, 0, stream>>>(bufA, W3, bufB, N);
    agg128_kernel<<<(N + 3) / 4, 256, 0, stream>>>((const bf16x2*)bufB, rowp, csr, dis, b3,
                                                   (bf16x2*)bufA, N, 0);

    // --- mean pool + head ---
    hipMemsetAsync(sums, 0, (size_t)G * HID * 4, stream);
    pool_kernel<<<dim3(G, 32), HID, 0, stream>>>(bufA, bat, N, sums);
    final_kernel<<<G, HID, 0, stream>>>(sums, bat, N, Wl, bl, (float*)d_out);
}